// Round 4
// baseline (152.275 us; speedup 1.0000x reference)
//
#include <hip/hip_runtime.h>

typedef __attribute__((ext_vector_type(8))) short short8;
typedef __attribute__((ext_vector_type(4))) float f32x4;

__device__ __forceinline__ float bf2f(unsigned short u) {
    union { unsigned int i; float f; } v; v.i = ((unsigned int)u) << 16; return v.f;
}
__device__ __forceinline__ unsigned short f2bf(float f) {
    union { float f; unsigned int i; } v; v.f = f;
    unsigned int r = v.i + 0x7fffu + ((v.i >> 16) & 1u);  // RNE
    return (unsigned short)(r >> 16);
}
__device__ __forceinline__ void gload16(const unsigned short* g, unsigned short* l) {
    __builtin_amdgcn_global_load_lds(
        (const __attribute__((address_space(1))) unsigned int*)g,
        (__attribute__((address_space(3))) unsigned int*)l, 16, 0, 0);
}

// ---------------------------------------------------------------------------
// 8-wave GEMM: C[M][1024](bf16) = A[M][K](bf16) @ Bt[1024][K]^T(bf16) + bias
// BM=256; MODE 0: BN=256 (merged shared-transform, M=16384, sel by row half);
//         MODE 1: BN=128 (language-selected Wg1 stack, pitch 1024).
// 2-buffer LDS, counted vmcnt at tile top, 2 barriers/tile, 4 setprio MFMA
// clusters, XOR-swizzled LDS (verified 0 bank conflicts).
// ---------------------------------------------------------------------------
template<int K, int MODE>
__global__ __launch_bounds__(512, 2) void gemm8(
    const unsigned short* __restrict__ A,
    const unsigned short* __restrict__ Bta,
    const unsigned short* __restrict__ Btb,
    const float* __restrict__ biasa,
    const float* __restrict__ biasb,
    unsigned short* __restrict__ Cb,
    const int* __restrict__ lang)
{
    constexpr int BN  = (MODE == 0) ? 256 : 128;
    constexpr int MR  = (MODE == 0) ? 8 : 4;      // m-frags per wave
    constexpr int MPC = MR / 4;                   // m-frags per cluster (2 or 1)
    constexpr int NBLK = 1024 / BN;
    constexpr int LPT = 4 + BN / 64;              // gloads/thread/tile (8 or 6)
    constexpr int NT  = K / 64;

    __shared__ __align__(16) unsigned short As[2][256][64];
    __shared__ __align__(16) unsigned short Bs[2][BN][64];

    const int t = threadIdx.x;
    const int nwg = gridDim.x;                    // 256, multiple of 8
    const int bid = blockIdx.x;
    const int swz = (bid & 7) * (nwg >> 3) + (bid >> 3);
    const int mb = swz / NBLK;
    const int nb = swz % NBLK;
    const int gm0 = mb * 256, gn0 = nb * BN;

    const unsigned short* Bt;
    const float* bias;
    int sel = 0;
    if (MODE == 0) {
        sel = gm0 >> 13;
        Bt = sel ? Btb : Bta;
        bias = sel ? biasb : biasa;
    } else {
        const int l = lang[gm0 >> 9];
        Bt = Bta + (size_t)l * ((size_t)K * 1024);
        bias = biasa + l * 1024;
    }

    const int lane = t & 63, w = t >> 6;
    const int wm = (MODE == 0) ? (w >> 2) : (w >> 1);
    const int wn = (MODE == 0) ? (w & 3) : (w & 1);
    const int fr = lane & 15, g4 = lane >> 4, f7 = lane & 7;

    // staging: per-lane-linear LDS dest (row pitch 128B), pre-swizzled global col
    const int sr  = t >> 3;                       // 0..63
    const int gsw = ((t & 7) ^ (sr & 7)) * 8;
    const int lc  = (t & 7) * 8;
    const unsigned short* ag = A  + (size_t)(gm0 + sr) * K + gsw;
    const unsigned short* bg = Bt + (size_t)(gn0 + sr) * K + gsw;

    f32x4 acc[MR][4];
#pragma unroll
    for (int m = 0; m < MR; ++m)
#pragma unroll
        for (int n = 0; n < 4; ++n)
            acc[m][n] = (f32x4){0.f, 0.f, 0.f, 0.f};

    auto stage = [&](int buf, int k0) {
#pragma unroll
        for (int i = 0; i < 4; ++i)
            gload16(ag + (size_t)(i * 64) * K + k0, &As[buf][i * 64 + sr][lc]);
#pragma unroll
        for (int i = 0; i < BN / 64; ++i)
            gload16(bg + (size_t)(i * 64) * K + k0, &Bs[buf][i * 64 + sr][lc]);
    };

    stage(0, 0);
    if (NT > 1) stage(1, 64);

    for (int tt = 0; tt < NT; ++tt) {
        const int cur = tt & 1;
        if (tt + 1 < NT) asm volatile("s_waitcnt vmcnt(%0)" :: "i"(LPT) : "memory");
        else             asm volatile("s_waitcnt vmcnt(0)" ::: "memory");
        __builtin_amdgcn_s_barrier();
        asm volatile("" ::: "memory");
        __builtin_amdgcn_sched_barrier(0);

        // B fragments resident for the whole tile
        short8 bf_[4][2];
#pragma unroll
        for (int n = 0; n < 4; ++n)
#pragma unroll
            for (int kk = 0; kk < 2; ++kk)
                bf_[n][kk] = *(const short8*)&Bs[cur][wn * 64 + n * 16 + fr][((kk * 4 + g4) ^ f7) * 8];

        // 4 clusters: per-cluster A loads + setprio-wrapped MFMA
#pragma unroll
        for (int c = 0; c < 4; ++c) {
            short8 af_[MPC][2];
#pragma unroll
            for (int mm = 0; mm < MPC; ++mm)
#pragma unroll
                for (int kk = 0; kk < 2; ++kk)
                    af_[mm][kk] = *(const short8*)&As[cur][wm * (MR * 16) + (c * MPC + mm) * 16 + fr][((kk * 4 + g4) ^ f7) * 8];
            __builtin_amdgcn_s_setprio(1);
#pragma unroll
            for (int mm = 0; mm < MPC; ++mm)
#pragma unroll
                for (int n = 0; n < 4; ++n)
#pragma unroll
                    for (int kk = 0; kk < 2; ++kk)
                        acc[c * MPC + mm][n] = __builtin_amdgcn_mfma_f32_16x16x32_bf16(
                            af_[mm][kk], bf_[n][kk], acc[c * MPC + mm][n], 0, 0, 0);
            __builtin_amdgcn_s_setprio(0);
        }

        __builtin_amdgcn_sched_barrier(0);
        __builtin_amdgcn_s_barrier();
        asm volatile("" ::: "memory");
        if (tt + 2 < NT) stage(cur, (tt + 2) * 64);
    }

    // epilogue: D mapping col=lane&15, row=(lane>>4)*4+reg; bf16 store
    const int fq = lane >> 4;
    const size_t pitch  = (MODE == 0) ? 2048 : 1024;
    const size_t coloff = (MODE == 0) ? (size_t)sel * 1024 : 0;
    const int rbase = (MODE == 0) ? (gm0 & 8191) : gm0;
#pragma unroll
    for (int n = 0; n < 4; ++n) {
        const int col = gn0 + wn * 64 + n * 16 + fr;
        const float bv = bias[col];
#pragma unroll
        for (int m = 0; m < MR; ++m) {
            const int row0 = rbase + wm * (MR * 16) + m * 16 + fq * 4;
#pragma unroll
            for (int r = 0; r < 4; ++r)
                Cb[(size_t)(row0 + r) * pitch + coloff + col] = f2bf(acc[m][n][r] + bv);
        }
    }
}

// W [K][N] f32 -> Wt [N][K] bf16 (per blockIdx.z slab)
__global__ __launch_bounds__(256) void wt_bf16(
    const float* __restrict__ W, unsigned short* __restrict__ Wt, int K, int N)
{
    __shared__ float tile[32][33];
    W  += (size_t)blockIdx.z * K * N;
    Wt += (size_t)blockIdx.z * K * N;
    const int n0 = blockIdx.x * 32, k0 = blockIdx.y * 32;
    const int x = threadIdx.x & 31, y = threadIdx.x >> 5;
#pragma unroll
    for (int i = 0; i < 4; ++i)
        tile[y + 8 * i][x] = W[(size_t)(k0 + y + 8 * i) * N + n0 + x];
    __syncthreads();
#pragma unroll
    for (int i = 0; i < 4; ++i)
        Wt[(size_t)(n0 + y + 8 * i) * K + k0 + x] = f2bf(tile[x][y + 8 * i]);
}

// f32 -> bf16 elementwise (2048 elems / block)
__global__ __launch_bounds__(256) void conv_bf16(
    const float* __restrict__ in, unsigned short* __restrict__ out)
{
    const size_t i = ((size_t)blockIdx.x * 256 + threadIdx.x) * 8;
    const float4 a = ((const float4*)(in + i))[0];
    const float4 b = ((const float4*)(in + i))[1];
    ushort4 u, v;
    u.x = f2bf(a.x); u.y = f2bf(a.y); u.z = f2bf(a.z); u.w = f2bf(a.w);
    v.x = f2bf(b.x); v.y = f2bf(b.y); v.z = f2bf(b.z); v.w = f2bf(b.w);
    *(ushort4*)(out + i)     = u;
    *(ushort4*)(out + i + 4) = v;
}

// in-place LN(1024)+ReLU on combined halves (bf16). grid 16384: r=b>>1, half=b&1
__global__ __launch_bounds__(256) void ln_relu_c(
    unsigned short* __restrict__ comb,
    const float* __restrict__ gn, const float* __restrict__ bn,
    const float* __restrict__ gt, const float* __restrict__ btp)
{
    const int b = blockIdx.x, t = threadIdx.x;
    const int r = b >> 1, half = b & 1;
    unsigned short* p = comb + (size_t)r * 2048 + half * 1024 + t * 4;
    ushort4 u = *(const ushort4*)p;
    const float x0 = bf2f(u.x), x1 = bf2f(u.y), x2 = bf2f(u.z), x3 = bf2f(u.w);
    float s1 = x0 + x1 + x2 + x3;
    float s2 = x0 * x0 + x1 * x1 + x2 * x2 + x3 * x3;
#pragma unroll
    for (int off = 32; off > 0; off >>= 1) {
        s1 += __shfl_down(s1, off);
        s2 += __shfl_down(s2, off);
    }
    __shared__ float red[8];
    const int wid = t >> 6;
    if ((t & 63) == 0) { red[wid] = s1; red[4 + wid] = s2; }
    __syncthreads();
    s1 = red[0] + red[1] + red[2] + red[3];
    s2 = red[4] + red[5] + red[6] + red[7];
    const float mean = s1 * (1.0f / 1024.0f);
    const float var = fmaxf(s2 * (1.0f / 1024.0f) - mean * mean, 0.0f);
    const float rstd = rsqrtf(var + 1e-5f);
    const float* G  = half ? gt : gn;
    const float* Be = half ? btp : bn;
    const float4 g  = ((const float4*)G)[t];
    const float4 be = ((const float4*)Be)[t];
    u.x = f2bf(fmaxf((x0 - mean) * rstd * g.x + be.x, 0.0f));
    u.y = f2bf(fmaxf((x1 - mean) * rstd * g.y + be.y, 0.0f));
    u.z = f2bf(fmaxf((x2 - mean) * rstd * g.z + be.z, 0.0f));
    u.w = f2bf(fmaxf((x3 - mean) * rstd * g.w + be.w, 0.0f));
    *(ushort4*)p = u;
}

// Fused: LN(1024)+ReLU on preln row (lang gamma/beta) -> gate dots -> sigmoid
// -> scale combined halves -> f32 outputs. One block per row.
__global__ __launch_bounds__(256) void ln_gate(
    const unsigned short* __restrict__ preln, const unsigned short* __restrict__ comb,
    const float* __restrict__ gg, const float* __restrict__ bgb,
    const float* __restrict__ Wg2, const float* __restrict__ bg2,
    const int* __restrict__ lang,
    float* __restrict__ outN, float* __restrict__ outT)
{
    const int r = blockIdx.x, t = threadIdx.x;
    const int l = lang[r >> 9];
    const ushort4 u = *(const ushort4*)(preln + (size_t)r * 1024 + t * 4);
    const float x0 = bf2f(u.x), x1 = bf2f(u.y), x2 = bf2f(u.z), x3 = bf2f(u.w);
    float s1 = x0 + x1 + x2 + x3;
    float s2 = x0 * x0 + x1 * x1 + x2 * x2 + x3 * x3;
#pragma unroll
    for (int off = 32; off > 0; off >>= 1) {
        s1 += __shfl_down(s1, off);
        s2 += __shfl_down(s2, off);
    }
    __shared__ float red[8];
    const int wid = t >> 6;
    if ((t & 63) == 0) { red[wid] = s1; red[4 + wid] = s2; }
    __syncthreads();
    s1 = red[0] + red[1] + red[2] + red[3];
    s2 = red[4] + red[5] + red[6] + red[7];
    const float mean = s1 * (1.0f / 1024.0f);
    const float var = fmaxf(s2 * (1.0f / 1024.0f) - mean * mean, 0.0f);
    const float rstd = rsqrtf(var + 1e-5f);
    const float4 g  = ((const float4*)(gg + l * 1024))[t];
    const float4 be = ((const float4*)(bgb + l * 1024))[t];
    const float h0 = fmaxf((x0 - mean) * rstd * g.x + be.x, 0.0f);
    const float h1 = fmaxf((x1 - mean) * rstd * g.y + be.y, 0.0f);
    const float h2 = fmaxf((x2 - mean) * rstd * g.z + be.z, 0.0f);
    const float h3 = fmaxf((x3 - mean) * rstd * g.w + be.w, 0.0f);
    const float4* W = (const float4*)(Wg2 + (size_t)l * 2048);
    const float4 wa = W[t * 2], wb = W[t * 2 + 1];
    float d0 = h0 * wa.x + h1 * wa.z + h2 * wb.x + h3 * wb.z;
    float d1 = h0 * wa.y + h1 * wa.w + h2 * wb.y + h3 * wb.w;
#pragma unroll
    for (int off = 32; off > 0; off >>= 1) {
        d0 += __shfl_down(d0, off);
        d1 += __shfl_down(d1, off);
    }
    __syncthreads();                         // red[] reuse safety
    if ((t & 63) == 0) { red[wid] = d0; red[4 + wid] = d1; }
    __syncthreads();
    d0 = red[0] + red[1] + red[2] + red[3] + bg2[l * 2 + 0];
    d1 = red[4] + red[5] + red[6] + red[7] + bg2[l * 2 + 1];
    const float g0 = 1.0f / (1.0f + __expf(-d0));
    const float g1 = 1.0f / (1.0f + __expf(-d1));
    const ushort4 cn = *(const ushort4*)(comb + (size_t)r * 2048 + t * 4);
    const ushort4 ct = *(const ushort4*)(comb + (size_t)r * 2048 + 1024 + t * 4);
    float4 a, b;
    a.x = bf2f(cn.x) * g0; a.y = bf2f(cn.y) * g0; a.z = bf2f(cn.z) * g0; a.w = bf2f(cn.w) * g0;
    b.x = bf2f(ct.x) * g1; b.y = bf2f(ct.y) * g1; b.z = bf2f(ct.z) * g1; b.w = bf2f(ct.w) * g1;
    ((float4*)(outN + (size_t)r * 1024))[t] = a;
    ((float4*)(outT + (size_t)r * 1024))[t] = b;
}

extern "C" void kernel_launch(void* const* d_in, const int* in_sizes, int n_in,
                              void* d_out, int out_size, void* d_ws, size_t ws_size,
                              hipStream_t stream)
{
    const float* ner    = (const float*)d_in[0];
    const float* top    = (const float*)d_in[1];
    const int*   lang   = (const int*)d_in[2];
    const float* W_ner  = (const float*)d_in[3];
    const float* b_ner  = (const float*)d_in[4];
    const float* g_ner  = (const float*)d_in[5];
    const float* be_ner = (const float*)d_in[6];
    const float* W_top  = (const float*)d_in[7];
    const float* b_top  = (const float*)d_in[8];
    const float* g_top  = (const float*)d_in[9];
    const float* be_top = (const float*)d_in[10];
    const float* Wg1    = (const float*)d_in[11];
    const float* bg1    = (const float*)d_in[12];
    const float* gg     = (const float*)d_in[13];
    const float* bgb    = (const float*)d_in[14];
    const float* Wg2    = (const float*)d_in[15];
    const float* bg2    = (const float*)d_in[16];

    float* out  = (float*)d_out;
    float* outN = out;
    float* outT = out + 8388608;

    // ws layout (~80 MB): combined | actb (later preln2) | Wg1t
    char* ws = (char*)d_ws;
    unsigned short* combined = (unsigned short*)ws;                 // [8192][2048] bf16, 32MB
    unsigned short* actb     = (unsigned short*)(ws + 33554432);    // [16384][768] bf16, 24MB
    unsigned short* preln2   = (unsigned short*)(ws + 33554432);    // [8192][1024] bf16 overlays actb
    unsigned short* Wg1t     = (unsigned short*)(ws + 58720256);    // [5][1024][2048] bf16, 20MB
    unsigned short* W_nert   = (unsigned short*)outT;               // [1024][768] bf16 (d_out scratch)
    unsigned short* W_topt   = W_nert + 786432;                     // [1024][768]

    // weight prep: f32 [K][N] -> bf16 [N][K]
    wt_bf16<<<dim3(32, 24, 1), 256, 0, stream>>>(W_ner, W_nert, 768, 1024);
    wt_bf16<<<dim3(32, 24, 1), 256, 0, stream>>>(W_top, W_topt, 768, 1024);
    wt_bf16<<<dim3(32, 64, 5), 256, 0, stream>>>(Wg1, Wg1t, 2048, 1024);

    // activations f32 -> bf16, concatenated on M
    conv_bf16<<<3072, 256, 0, stream>>>(ner, actb);
    conv_bf16<<<3072, 256, 0, stream>>>(top, actb + 6291456);

    // merged shared-transform GEMM: [16384][768] -> combined pre-LN (bf16)
    gemm8<768, 0><<<256, 512, 0, stream>>>(
        actb, W_nert, W_topt, b_ner, b_top, combined, nullptr);
    ln_relu_c<<<16384, 256, 0, stream>>>(combined, g_ner, be_ner, g_top, be_top);

    // gate MLP first layer (language-selected): combined @ Wg1t[l] -> preln2
    gemm8<2048, 1><<<256, 512, 0, stream>>>(
        combined, Wg1t, nullptr, bg1, nullptr, preln2, lang);

    // fused LN2 + gate dots + sigmoid + output scaling
    ln_gate<<<8192, 256, 0, stream>>>(preln2, combined, gg, bgb, Wg2, bg2, lang, outN, outT);
}

// Round 5
// 148.817 us; speedup vs baseline: 1.0232x; 1.0232x over previous
//
#include <hip/hip_runtime.h>

typedef __attribute__((ext_vector_type(8))) short short8;
typedef __attribute__((ext_vector_type(4))) float f32x4;

__device__ __forceinline__ float bf2f(unsigned short u) {
    union { unsigned int i; float f; } v; v.i = ((unsigned int)u) << 16; return v.f;
}
__device__ __forceinline__ unsigned short f2bf(float f) {
    union { float f; unsigned int i; } v; v.f = f;
    unsigned int r = v.i + 0x7fffu + ((v.i >> 16) & 1u);  // RNE
    return (unsigned short)(r >> 16);
}
__device__ __forceinline__ void gload16(const unsigned short* g, unsigned short* l) {
    __builtin_amdgcn_global_load_lds(
        (const __attribute__((address_space(1))) unsigned int*)g,
        (__attribute__((address_space(3))) unsigned int*)l, 16, 0, 0);
}

// ---------------------------------------------------------------------------
// 8-phase 8-wave GEMM (m201-style): C[M][1024](bf16) = A[M][K] @ Bt[1024][K]^T + bias
// BM=256. MODE 0: BN=256, 4 phases/K-tile (merged shared transform, M=16384).
//         MODE 1: BN=128, 2 phases/K-tile (language-selected Wg1, M=8192).
// Per phase: {ds_read subtile || stage half-tile -> barrier -> lgkmcnt(0) ->
//            setprio(1) 16 MFMA setprio(0) -> barrier}. Counted vmcnt(6/4)
//            once per K-tile; never 0 in steady state.
// A stored h-split: LDS row = (mf>>2)*128 + wm*64 + (mf&3)*16 + fr, so half h
// is exactly the region consumed in phases {0,1} (h=0) / {2,3} (h=1).
// ---------------------------------------------------------------------------
template<int K, int MODE>
__global__ __launch_bounds__(512, 2) void gemm8(
    const unsigned short* __restrict__ A,
    const unsigned short* __restrict__ Bta,
    const unsigned short* __restrict__ Btb,
    const float* __restrict__ biasa,
    const float* __restrict__ biasb,
    unsigned short* __restrict__ Cb,
    const int* __restrict__ lang)
{
    constexpr int BN   = (MODE == 0) ? 256 : 128;
    constexpr int NBLK = 1024 / BN;
    constexpr int NT   = K / 64;
    constexpr int NPH  = (MODE == 0) ? 4 : 2;   // phases per K-tile
    constexpr int MPP  = 8 / NPH;               // m-frags per phase
    constexpr int NR   = (MODE == 0) ? 4 : 2;   // n-frags per wave
    constexpr int WNS  = BN / 4;                // wave col span
    constexpr int VN   = (MODE == 0) ? 6 : 4;   // steady-state vmcnt

    __shared__ __align__(16) unsigned short As[2][256][64];
    __shared__ __align__(16) unsigned short Bs[2][BN][64];

    const int t = threadIdx.x;
    const int nwg = gridDim.x;                  // 256, multiple of 8
    const int bid = blockIdx.x;
    const int swz = (bid & 7) * (nwg >> 3) + (bid >> 3);
    const int gm0 = (swz / NBLK) * 256;
    const int gn0 = (swz % NBLK) * BN;

    const unsigned short* Bt;
    const float* bias;
    int sel = 0;
    if (MODE == 0) {
        sel = gm0 >> 13;
        Bt = sel ? Btb : Bta;
        bias = sel ? biasb : biasa;
    } else {
        const int l = lang[gm0 >> 9];
        Bt = Bta + (size_t)l * ((size_t)K * 1024);
        bias = biasa + l * 1024;
    }

    const int lane = t & 63, w = t >> 6;
    const int wm = w >> 2, wn = w & 3;          // 2M x 4N waves
    const int fr = lane & 15, g4 = lane >> 4, f7 = lane & 7;

    // staging: linear LDS dest, pre-swizzled global source col (rule #21)
    const int sr  = t >> 3;                     // 0..63
    const int gsw = ((t & 7) ^ (sr & 7)) * 8;
    const int lc  = (t & 7) * 8;
    const unsigned short* agb = A  + (size_t)(gm0 + sr) * K + gsw;
    const unsigned short* bgb = Bt + (size_t)(gn0 + sr) * K + gsw;

    f32x4 acc[8][NR];
#pragma unroll
    for (int m = 0; m < 8; ++m)
#pragma unroll
        for (int n = 0; n < NR; ++n)
            acc[m][n] = (f32x4){0.f, 0.f, 0.f, 0.f};

    // stage half-tile: 2 gload16/thread. A half h: LDS rows h*128+[0,128),
    // global rows j*128 + h*64 + sr. B half h: identity rows h*128+j*64+sr.
    auto stA = [&](int buf, int h, int kb) {
#pragma unroll
        for (int j = 0; j < 2; ++j)
            gload16(agb + (size_t)(j * 128 + h * 64) * K + kb,
                    &As[buf][h * 128 + j * 64 + sr][lc]);
    };
    auto stB = [&](int buf, int h, int kb) {
#pragma unroll
        for (int j = 0; j < 2; ++j)
            gload16(bgb + (size_t)(h * 128 + j * 64) * K + kb,
                    &Bs[buf][h * 128 + j * 64 + sr][lc]);
    };

#define RDA(Q)                                                                \
    _Pragma("unroll")                                                         \
    for (int i = 0; i < MPP; ++i) {                                           \
        const int mf = (Q) * MPP + i;                                         \
        const int row = (mf >> 2) * 128 + wm * 64 + (mf & 3) * 16 + fr;       \
        _Pragma("unroll")                                                     \
        for (int kk = 0; kk < 2; ++kk)                                        \
            af_[i][kk] = *(const short8*)&As[c][row][((kk * 4 + g4) ^ f7) * 8];\
    }

#define RDB()                                                                 \
    _Pragma("unroll")                                                         \
    for (int n = 0; n < NR; ++n) {                                            \
        const int row = wn * WNS + n * 16 + fr;                               \
        _Pragma("unroll")                                                     \
        for (int kk = 0; kk < 2; ++kk)                                        \
            bf_[n][kk] = *(const short8*)&Bs[c][row][((kk * 4 + g4) ^ f7) * 8];\
    }

#define MFMA16(Q)                                                             \
    __builtin_amdgcn_s_setprio(1);                                            \
    _Pragma("unroll")                                                         \
    for (int kk = 0; kk < 2; ++kk)                                            \
        _Pragma("unroll")                                                     \
        for (int i = 0; i < MPP; ++i)                                         \
            _Pragma("unroll")                                                 \
            for (int n = 0; n < NR; ++n)                                      \
                acc[(Q) * MPP + i][n] = __builtin_amdgcn_mfma_f32_16x16x32_bf16(\
                    af_[i][kk], bf_[n][kk], acc[(Q) * MPP + i][n], 0, 0, 0);  \
    __builtin_amdgcn_s_setprio(0);

#define PH_TOP()  __builtin_amdgcn_sched_barrier(0); __builtin_amdgcn_s_barrier(); \
                  asm volatile("s_waitcnt lgkmcnt(0)" ::: "memory");               \
                  __builtin_amdgcn_sched_barrier(0);
#define PH_BOT()  __builtin_amdgcn_sched_barrier(0); __builtin_amdgcn_s_barrier();

    // prologue: tile0 complete + tile1 all-but-Ah1; counted drain; barrier
    if (MODE == 0) {
        stB(0, 0, 0); stB(0, 1, 0); stA(0, 0, 0); stA(0, 1, 0);
        stB(1, 0, 64); stB(1, 1, 64); stA(1, 0, 64);
        asm volatile("s_waitcnt vmcnt(6)" ::: "memory");
    } else {
        stB(0, 0, 0); stA(0, 0, 0); stA(0, 1, 0);
        stB(1, 0, 64); stA(1, 0, 64);
        asm volatile("s_waitcnt vmcnt(4)" ::: "memory");
    }
    __builtin_amdgcn_s_barrier();

#pragma unroll 2
    for (int u = 0; u < NT; ++u) {
        const int c = u & 1;
        const int kb1 = (u + 1) * 64, kb2 = (u + 2) * 64;
        const bool s1 = (u + 1 < NT), s2 = (u + 2 < NT);
        short8 bf_[NR][2], af_[MPP][2];

        // ---- phase 0: B-all + A quad 0; stage Ah1(u+1) -> other dbuf ----
        RDB();
        RDA(0);
        if (s1) stA(c ^ 1, 1, kb1);
        PH_TOP();
        MFMA16(0);
        PH_BOT();

        if (MODE == 0) {
            // ---- phase 1: A quad 1; stage Bh0(u+2) (B region free after p0) ----
            RDA(1);
            if (s2) stB(c, 0, kb2);
            PH_TOP();
            MFMA16(1);
            PH_BOT();
            // ---- phase 2: A quad 2; stage Bh1(u+2) ----
            RDA(2);
            if (s2) stB(c, 1, kb2);
            PH_TOP();
            MFMA16(2);
            PH_BOT();
            // ---- phase 3: A quad 3; stage Ah0(u+2); counted vmcnt ----
            RDA(3);
            if (s2) stA(c, 0, kb2);
            if (s2) asm volatile("s_waitcnt vmcnt(%0)" :: "i"(VN) : "memory");
            else    asm volatile("s_waitcnt vmcnt(0)" ::: "memory");
            PH_TOP();
            MFMA16(3);
            PH_BOT();
        } else {
            // ---- phase 1: A mf4-7; stage Bh(u+2)+Ah0(u+2); counted vmcnt ----
            RDA(1);
            if (s2) { stB(c, 0, kb2); stA(c, 0, kb2); }
            if (s2) asm volatile("s_waitcnt vmcnt(%0)" :: "i"(VN) : "memory");
            else    asm volatile("s_waitcnt vmcnt(0)" ::: "memory");
            PH_TOP();
            MFMA16(1);
            PH_BOT();
        }
    }

    // epilogue: D mapping col=lane&15, row=(lane>>4)*4+reg; bf16 store
    const int fq = lane >> 4;
    const size_t pitch  = (MODE == 0) ? 2048 : 1024;
    const size_t coloff = (MODE == 0) ? (size_t)sel * 1024 : 0;
    const int rbase = (MODE == 0) ? (gm0 & 8191) : gm0;
#pragma unroll
    for (int n = 0; n < NR; ++n) {
        const int col = gn0 + wn * WNS + n * 16 + fr;
        const float bv = bias[col];
#pragma unroll
        for (int m = 0; m < 8; ++m) {
            const int row0 = rbase + wm * 128 + m * 16 + fq * 4;
#pragma unroll
            for (int r = 0; r < 4; ++r)
                Cb[(size_t)(row0 + r) * pitch + coloff + col] = f2bf(acc[m][n][r] + bv);
        }
    }
#undef RDA
#undef RDB
#undef MFMA16
#undef PH_TOP
#undef PH_BOT
}

// W [K][N] f32 -> Wt [N][K] bf16 (per blockIdx.z slab)
__global__ __launch_bounds__(256) void wt_bf16(
    const float* __restrict__ W, unsigned short* __restrict__ Wt, int K, int N)
{
    __shared__ float tile[32][33];
    W  += (size_t)blockIdx.z * K * N;
    Wt += (size_t)blockIdx.z * K * N;
    const int n0 = blockIdx.x * 32, k0 = blockIdx.y * 32;
    const int x = threadIdx.x & 31, y = threadIdx.x >> 5;
#pragma unroll
    for (int i = 0; i < 4; ++i)
        tile[y + 8 * i][x] = W[(size_t)(k0 + y + 8 * i) * N + n0 + x];
    __syncthreads();
#pragma unroll
    for (int i = 0; i < 4; ++i)
        Wt[(size_t)(n0 + y + 8 * i) * K + k0 + x] = f2bf(tile[x][y + 8 * i]);
}

// f32 -> bf16 elementwise (2048 elems / block)
__global__ __launch_bounds__(256) void conv_bf16(
    const float* __restrict__ in, unsigned short* __restrict__ out)
{
    const size_t i = ((size_t)blockIdx.x * 256 + threadIdx.x) * 8;
    const float4 a = ((const float4*)(in + i))[0];
    const float4 b = ((const float4*)(in + i))[1];
    ushort4 u, v;
    u.x = f2bf(a.x); u.y = f2bf(a.y); u.z = f2bf(a.z); u.w = f2bf(a.w);
    v.x = f2bf(b.x); v.y = f2bf(b.y); v.z = f2bf(b.z); v.w = f2bf(b.w);
    *(ushort4*)(out + i)     = u;
    *(ushort4*)(out + i + 4) = v;
}

// in-place LN(1024)+ReLU on combined halves (bf16). grid 16384: r=b>>1, half=b&1
__global__ __launch_bounds__(256) void ln_relu_c(
    unsigned short* __restrict__ comb,
    const float* __restrict__ gn, const float* __restrict__ bn,
    const float* __restrict__ gt, const float* __restrict__ btp)
{
    const int b = blockIdx.x, t = threadIdx.x;
    const int r = b >> 1, half = b & 1;
    unsigned short* p = comb + (size_t)r * 2048 + half * 1024 + t * 4;
    ushort4 u = *(const ushort4*)p;
    const float x0 = bf2f(u.x), x1 = bf2f(u.y), x2 = bf2f(u.z), x3 = bf2f(u.w);
    float s1 = x0 + x1 + x2 + x3;
    float s2 = x0 * x0 + x1 * x1 + x2 * x2 + x3 * x3;
#pragma unroll
    for (int off = 32; off > 0; off >>= 1) {
        s1 += __shfl_down(s1, off);
        s2 += __shfl_down(s2, off);
    }
    __shared__ float red[8];
    const int wid = t >> 6;
    if ((t & 63) == 0) { red[wid] = s1; red[4 + wid] = s2; }
    __syncthreads();
    s1 = red[0] + red[1] + red[2] + red[3];
    s2 = red[4] + red[5] + red[6] + red[7];
    const float mean = s1 * (1.0f / 1024.0f);
    const float var = fmaxf(s2 * (1.0f / 1024.0f) - mean * mean, 0.0f);
    const float rstd = rsqrtf(var + 1e-5f);
    const float* G  = half ? gt : gn;
    const float* Be = half ? btp : bn;
    const float4 g  = ((const float4*)G)[t];
    const float4 be = ((const float4*)Be)[t];
    u.x = f2bf(fmaxf((x0 - mean) * rstd * g.x + be.x, 0.0f));
    u.y = f2bf(fmaxf((x1 - mean) * rstd * g.y + be.y, 0.0f));
    u.z = f2bf(fmaxf((x2 - mean) * rstd * g.z + be.z, 0.0f));
    u.w = f2bf(fmaxf((x3 - mean) * rstd * g.w + be.w, 0.0f));
    *(ushort4*)p = u;
}

// Fused: LN(1024)+ReLU (lang gamma/beta) -> gate dots -> sigmoid -> scale -> f32 out
__global__ __launch_bounds__(256) void ln_gate(
    const unsigned short* __restrict__ preln, const unsigned short* __restrict__ comb,
    const float* __restrict__ gg, const float* __restrict__ bgb,
    const float* __restrict__ Wg2, const float* __restrict__ bg2,
    const int* __restrict__ lang,
    float* __restrict__ outN, float* __restrict__ outT)
{
    const int r = blockIdx.x, t = threadIdx.x;
    const int l = lang[r >> 9];
    const ushort4 u = *(const ushort4*)(preln + (size_t)r * 1024 + t * 4);
    const float x0 = bf2f(u.x), x1 = bf2f(u.y), x2 = bf2f(u.z), x3 = bf2f(u.w);
    float s1 = x0 + x1 + x2 + x3;
    float s2 = x0 * x0 + x1 * x1 + x2 * x2 + x3 * x3;
#pragma unroll
    for (int off = 32; off > 0; off >>= 1) {
        s1 += __shfl_down(s1, off);
        s2 += __shfl_down(s2, off);
    }
    __shared__ float red[8];
    const int wid = t >> 6;
    if ((t & 63) == 0) { red[wid] = s1; red[4 + wid] = s2; }
    __syncthreads();
    s1 = red[0] + red[1] + red[2] + red[3];
    s2 = red[4] + red[5] + red[6] + red[7];
    const float mean = s1 * (1.0f / 1024.0f);
    const float var = fmaxf(s2 * (1.0f / 1024.0f) - mean * mean, 0.0f);
    const float rstd = rsqrtf(var + 1e-5f);
    const float4 g  = ((const float4*)(gg + l * 1024))[t];
    const float4 be = ((const float4*)(bgb + l * 1024))[t];
    const float h0 = fmaxf((x0 - mean) * rstd * g.x + be.x, 0.0f);
    const float h1 = fmaxf((x1 - mean) * rstd * g.y + be.y, 0.0f);
    const float h2 = fmaxf((x2 - mean) * rstd * g.z + be.z, 0.0f);
    const float h3 = fmaxf((x3 - mean) * rstd * g.w + be.w, 0.0f);
    const float4* W = (const float4*)(Wg2 + (size_t)l * 2048);
    const float4 wa = W[t * 2], wb = W[t * 2 + 1];
    float d0 = h0 * wa.x + h1 * wa.z + h2 * wb.x + h3 * wb.z;
    float d1 = h0 * wa.y + h1 * wa.w + h2 * wb.y + h3 * wb.w;
#pragma unroll
    for (int off = 32; off > 0; off >>= 1) {
        d0 += __shfl_down(d0, off);
        d1 += __shfl_down(d1, off);
    }
    __syncthreads();
    if ((t & 63) == 0) { red[wid] = d0; red[4 + wid] = d1; }
    __syncthreads();
    d0 = red[0] + red[1] + red[2] + red[3] + bg2[l * 2 + 0];
    d1 = red[4] + red[5] + red[6] + red[7] + bg2[l * 2 + 1];
    const float g0 = 1.0f / (1.0f + __expf(-d0));
    const float g1 = 1.0f / (1.0f + __expf(-d1));
    const ushort4 cn = *(const ushort4*)(comb + (size_t)r * 2048 + t * 4);
    const ushort4 ct = *(const ushort4*)(comb + (size_t)r * 2048 + 1024 + t * 4);
    float4 a, b;
    a.x = bf2f(cn.x) * g0; a.y = bf2f(cn.y) * g0; a.z = bf2f(cn.z) * g0; a.w = bf2f(cn.w) * g0;
    b.x = bf2f(ct.x) * g1; b.y = bf2f(ct.y) * g1; b.z = bf2f(ct.z) * g1; b.w = bf2f(ct.w) * g1;
    ((float4*)(outN + (size_t)r * 1024))[t] = a;
    ((float4*)(outT + (size_t)r * 1024))[t] = b;
}

extern "C" void kernel_launch(void* const* d_in, const int* in_sizes, int n_in,
                              void* d_out, int out_size, void* d_ws, size_t ws_size,
                              hipStream_t stream)
{
    const float* ner    = (const float*)d_in[0];
    const float* top    = (const float*)d_in[1];
    const int*   lang   = (const int*)d_in[2];
    const float* W_ner  = (const float*)d_in[3];
    const float* b_ner  = (const float*)d_in[4];
    const float* g_ner  = (const float*)d_in[5];
    const float* be_ner = (const float*)d_in[6];
    const float* W_top  = (const float*)d_in[7];
    const float* b_top  = (const float*)d_in[8];
    const float* g_top  = (const float*)d_in[9];
    const float* be_top = (const float*)d_in[10];
    const float* Wg1    = (const float*)d_in[11];
    const float* bg1    = (const float*)d_in[12];
    const float* gg     = (const float*)d_in[13];
    const float* bgb    = (const float*)d_in[14];
    const float* Wg2    = (const float*)d_in[15];
    const float* bg2    = (const float*)d_in[16];

    float* out  = (float*)d_out;
    float* outN = out;
    float* outT = out + 8388608;

    // ws layout (~80 MB): combined | actb (later preln2) | Wg1t
    char* ws = (char*)d_ws;
    unsigned short* combined = (unsigned short*)ws;                 // [8192][2048] bf16, 32MB
    unsigned short* actb     = (unsigned short*)(ws + 33554432);    // [16384][768] bf16, 24MB
    unsigned short* preln2   = (unsigned short*)(ws + 33554432);    // [8192][1024] bf16 overlays actb
    unsigned short* Wg1t     = (unsigned short*)(ws + 58720256);    // [5][1024][2048] bf16, 20MB
    unsigned short* W_nert   = (unsigned short*)outT;               // [1024][768] bf16 (d_out scratch)
    unsigned short* W_topt   = W_nert + 786432;                     // [1024][768]

    // weight prep: f32 [K][N] -> bf16 [N][K]
    wt_bf16<<<dim3(32, 24, 1), 256, 0, stream>>>(W_ner, W_nert, 768, 1024);
    wt_bf16<<<dim3(32, 24, 1), 256, 0, stream>>>(W_top, W_topt, 768, 1024);
    wt_bf16<<<dim3(32, 64, 5), 256, 0, stream>>>(Wg1, Wg1t, 2048, 1024);

    // activations f32 -> bf16, concatenated on M
    conv_bf16<<<3072, 256, 0, stream>>>(ner, actb);
    conv_bf16<<<3072, 256, 0, stream>>>(top, actb + 6291456);

    // merged shared-transform GEMM: [16384][768] -> combined pre-LN (bf16)
    gemm8<768, 0><<<256, 512, 0, stream>>>(
        actb, W_nert, W_topt, b_ner, b_top, combined, nullptr);
    ln_relu_c<<<16384, 256, 0, stream>>>(combined, g_ner, be_ner, g_top, be_top);

    // gate MLP first layer (language-selected): combined @ Wg1t[l] -> preln2
    gemm8<2048, 1><<<256, 512, 0, stream>>>(
        combined, Wg1t, nullptr, bg1, nullptr, preln2, lang);

    // fused LN2 + gate dots + sigmoid + output scaling
    ln_gate<<<8192, 256, 0, stream>>>(preln2, combined, gg, bgb, Wg2, bg2, lang, outN, outT);
}